// Round 12
// baseline (78.309 us; speedup 1.0000x reference)
//
#include <hip/hip_runtime.h>
#include <hip/hip_bf16.h>

#define BB 4
#define NN 2048
#define FIN 128
#define NH 4
#define DH 32
#define NS 0.2f

typedef unsigned int u32;
typedef unsigned short u16;
typedef unsigned long long u64;
typedef __attribute__((ext_vector_type(8))) short short8;
typedef __attribute__((ext_vector_type(4))) float f32x4;
typedef __attribute__((ext_vector_type(4))) unsigned int u32x4;

// ws float offsets
#define OFF_ES 0          // [16][2048] f32
#define OFF_ED 32768      // [16][2048] f32
#define OFF_PQ 65536      // [16][2048] u32 (bf16 Q hi | bf16 P lo)
#define OFF_M  131072     // [16]
#define OFF_HT 131088     // u16 [16][32][2048] = 1048576 u16 = 524288 floats
#define OFF_BITS 655376   // u32 [4][2048][64] = 524288 u32

__device__ __forceinline__ u16 f2bf_rne(float f) {
  unsigned u = __float_as_uint(f);
  return (u16)((u + 0x7fffu + ((u >> 16) & 1u)) >> 16);
}

__device__ __forceinline__ int bitmask(u32 w, int e) {
#if __has_builtin(__builtin_amdgcn_sbfe)
  return __builtin_amdgcn_sbfe((int)w, e, 1);     // v_bfe_i32: 0 or -1
#else
  return ((int)(w << (31 - e))) >> 31;
#endif
}

// ---------------- K0: fused pack (2048 blocks) + proj (512 blocks), 0 LDS ---
__global__ __launch_bounds__(256) void k_pp(
    const int* __restrict__ adj, u32* __restrict__ bits,
    const float* __restrict__ x, const float* __restrict__ W,
    const float* __restrict__ a, u16* __restrict__ hT,
    float* __restrict__ e_src, float* __restrict__ e_dst) {
  const int bid = blockIdx.x;
  const int tid = threadIdx.x;

  if (bid % 5 != 0) {
    // ---- pack role: pid in [0,2048), 4 adj rows per block ----
    const int pid = bid - bid / 5 - 1;
    const int row = (pid << 2) | (tid >> 6);  // b*2048+i
    const int lane = tid & 63;
    const int* src = adj + (size_t)row * NN;
    u32* dst = bits + (size_t)row * 64;
#pragma unroll 8
    for (int it = 0; it < 32; ++it) {
      const int v = src[it * 64 + lane];
      const u64 m = __ballot(v != 0);
      if (lane == 0) *(u64*)(dst + it * 2) = m;
    }
    return;
  }

  // ---- proj role: pid in [0,512), 16 x-rows per block, W direct from L2 ----
  const int pid = bid / 5;
  const int f = tid & 127, g = tid >> 7;
  const int rb = pid * 16 + g * 8;
  const int head = f >> 5, d = f & 31;
  const int b = rb >> 11, n0 = rb & (NN - 1);
  const int bh = b * NH + head;
  const float a_s = a[head * (2 * DH) + d];
  const float a_d = a[head * (2 * DH) + DH + d];

  float acc[8];
#pragma unroll
  for (int r = 0; r < 8; ++r) acc[r] = 0.f;

  const float* xb = x + (size_t)rb * FIN;  // wave-uniform -> s_loads
#pragma unroll 4
  for (int k = 0; k < FIN; ++k) {
    const float wv = W[k * 128 + f];       // coalesced 256B/wave, L1/L2-hot
#pragma unroll
    for (int r = 0; r < 8; ++r) acc[r] = fmaf(wv, xb[r * FIN + k], acc[r]);
  }

  u16 hs[8];
#pragma unroll
  for (int r = 0; r < 8; ++r) hs[r] = f2bf_rne(acc[r]);
  u16* dst = hT + ((size_t)bh * DH + d) * NN + n0;
  *(int4*)dst = *(int4*)&hs[0];

#pragma unroll
  for (int r = 0; r < 8; ++r) {
    float s1 = acc[r] * a_s;
    float s2 = acc[r] * a_d;
#pragma unroll
    for (int off = 16; off >= 1; off >>= 1) {
      s1 += __shfl_xor(s1, off);
      s2 += __shfl_xor(s2, off);
    }
    if (d == 0) {
      e_src[(size_t)bh * NN + n0 + r] = s1;
      e_dst[(size_t)bh * NN + n0 + r] = s2;
    }
  }
}

// ---------------- K1.5: per-bh max + packed bf16 P/Q table ------------------
__global__ __launch_bounds__(64) void k_prep(
    const float* __restrict__ e_dst, u32* __restrict__ PQ,
    float* __restrict__ M) {
  const int bh = blockIdx.x >> 3, seg = blockIdx.x & 7;
  const int lane = threadIdx.x;
  const float* ed = e_dst + (size_t)bh * NN;
  float m = -1e30f;
#pragma unroll
  for (int t = 0; t < 32; ++t) m = fmaxf(m, ed[t * 64 + lane]);
#pragma unroll
  for (int off = 32; off >= 1; off >>= 1) m = fmaxf(m, __shfl_xor(m, off));
  if (seg == 0 && lane == 0) M[bh] = m;
#pragma unroll
  for (int t = 0; t < 4; ++t) {
    const int j = seg * 256 + t * 64 + lane;
    const float e = ed[j];
    const u32 pb = f2bf_rne(__expf(e));
    const u32 qb = f2bf_rne(__expf(NS * e));
    PQ[(size_t)bh * NN + j] = (qb << 16) | pb;
  }
}

// ---------------- K2: LDS-staged weights->MFMA->direct output ---------------
// 32 rows/block, 4 waves = 4 j-quarters, grid 1024. hT via wave-private LDS
// (coalesced, swizzled, dbuf); PQ prefetched 1 s-iter ahead; bits fully
// hoisted to registers (kills the per-iter 16-line gathers); denominators on
// the matrix pipe (ones-column MFMA).
__global__ __launch_bounds__(256) void k_attn(
    const u16* __restrict__ hT, const float* __restrict__ e_src,
    const u32* __restrict__ PQv, const float* __restrict__ Mv,
    const u32* __restrict__ bits, float* __restrict__ out) {
  // [wave][dbuf][32 d][64 j] u16 = 32 KB; epilogue part/sp aliased on top.
  __shared__ __align__(16) u16 smem[4][2][32 * 64];

  const int bid = blockIdx.x;          // 16 bh x 64 row-tiles
  const int bh = bid >> 6;
  const int it = bid & 63;
  const int b = bh >> 2, head = bh & 3;

  const int w = threadIdx.x >> 6;      // j-quarter
  const int lane = threadIdx.x & 63;
  const int lg = lane >> 4, lm = lane & 15;

  const int i0 = it * 32 + lm;
  const int i1 = i0 + 16;
  const float m = Mv[bh];
  const float es0 = e_src[(size_t)bh * NN + i0];
  const float es1 = e_src[(size_t)bh * NN + i1];
  const float mr0 = es0 + m, mr1 = es1 + m;
  const float mi0 = fmaxf(mr0, NS * mr0), mi1 = fmaxf(mr1, NS * mr1);
  const float A0 = __expf(es0 - mi0), B0 = __expf(NS * es0 - mi0);
  const float A1 = __expf(es1 - mi1), B1 = __expf(NS * es1 - mi1);
  // w = exp(lrelu(es+ed)-mi) = max(A*P_j, B*Q_j)   (exp monotone, exact)

  const u32* PQb = PQv + (size_t)bh * NN + w * 512;
  const u16* hb = hT + (size_t)bh * DH * NN + w * 512;   // [d][j-quarter]
  const u32* br0 = bits + ((size_t)b * NN + i0) * 64 + w * 16;
  const u32* br1 = bits + ((size_t)b * NN + i1) * 64 + w * 16;
  const int shamt = lg * 8;
  const int jb = lg * 8;

  // hoist ALL bits for this wave's j-quarter into registers (8 x int4 loads)
  u32 wd0[16], wd1[16];
#pragma unroll
  for (int q = 0; q < 4; ++q) {
    const u32x4 v0 = *(const u32x4*)(br0 + q * 4);
    const u32x4 v1 = *(const u32x4*)(br1 + q * 4);
#pragma unroll
    for (int k2 = 0; k2 < 4; ++k2) { wd0[q * 4 + k2] = v0[k2]; wd1[q * 4 + k2] = v1[k2]; }
  }

  // staging lane roles: instr t loads data rows d = t*8+sd, 16B at j-offset sj.
  const int sd = lane >> 3;
  const int sj = (lane & 7) * 8;
  u16* stg0 = &smem[w][0][0];
  u16* stg1 = &smem[w][1][0];
  const int woff = (sd * 64 + sj) ^ (sd << 3);   // row sd, swizzle (d&7)<<3

  short8 ones;
#pragma unroll
  for (int e = 0; e < 8; ++e) ones[e] = (short)0x3F80;  // bf16 1.0

  f32x4 acc00 = {0,0,0,0}, acc01 = {0,0,0,0};
  f32x4 acc10 = {0,0,0,0}, acc11 = {0,0,0,0};
  f32x4 accS0 = {0,0,0,0}, accS1 = {0,0,0,0};

  // prologue: stage superchunk 0 + prefetch PQ for s=0
  {
    int4 r0 = *(const int4*)(hb + (size_t)(0 * 8 + sd) * NN + sj);
    int4 r1 = *(const int4*)(hb + (size_t)(1 * 8 + sd) * NN + sj);
    int4 r2 = *(const int4*)(hb + (size_t)(2 * 8 + sd) * NN + sj);
    int4 r3 = *(const int4*)(hb + (size_t)(3 * 8 + sd) * NN + sj);
    *(int4*)(stg0 + woff) = r0;
    *(int4*)(stg0 + woff + 1 * 512) = r1;
    *(int4*)(stg0 + woff + 2 * 512) = r2;
    *(int4*)(stg0 + woff + 3 * 512) = r3;
  }
  u32x4 pqa0_c = *(const u32x4*)(PQb + jb);
  u32x4 pqb0_c = *(const u32x4*)(PQb + jb + 4);
  u32x4 pqa1_c = *(const u32x4*)(PQb + 32 + jb);
  u32x4 pqb1_c = *(const u32x4*)(PQb + 32 + jb + 4);

  const int ra0 = (lm * 64) ^ ((lm & 7) << 3);  // swizzled base for d=lm row

#pragma unroll
  for (int s = 0; s < 8; ++s) {
    u16* cur = (s & 1) ? stg1 : stg0;
    u16* nxt = (s & 1) ? stg0 : stg1;
    int4 n0, n1, n2, n3;
    u32x4 pqa0_n, pqb0_n, pqa1_n, pqb1_n;
    if (s < 7) {  // issue all next-s global loads before this s's compute
      const u16* g = hb + (s + 1) * 64;
      n0 = *(const int4*)(g + (size_t)(0 * 8 + sd) * NN + sj);
      n1 = *(const int4*)(g + (size_t)(1 * 8 + sd) * NN + sj);
      n2 = *(const int4*)(g + (size_t)(2 * 8 + sd) * NN + sj);
      n3 = *(const int4*)(g + (size_t)(3 * 8 + sd) * NN + sj);
      const u32* pqn = PQb + (s + 1) * 64;
      pqa0_n = *(const u32x4*)(pqn + jb);
      pqb0_n = *(const u32x4*)(pqn + jb + 4);
      pqa1_n = *(const u32x4*)(pqn + 32 + jb);
      pqb1_n = *(const u32x4*)(pqn + 32 + jb + 4);
    }
#pragma unroll
    for (int c = 0; c < 2; ++c) {
      const int jl = c * 32 + jb;
      const u32x4 pqa = c ? pqa1_c : pqa0_c;   // compile-time select
      const u32x4 pqb = c ? pqb1_c : pqb0_c;
      const short8 hv0 = *(const short8*)(cur + (ra0 ^ jl));
      const short8 hv1 = *(const short8*)(cur + ((ra0 ^ jl) + 16 * 64));
      const u32 wsh0 = wd0[s * 2 + c] >> shamt;   // static index (unrolled)
      const u32 wsh1 = wd1[s * 2 + c] >> shamt;
      short8 af0, af1;
#pragma unroll
      for (int e = 0; e < 8; ++e) {
        const u32 pq = (e < 4) ? pqa[e] : pqb[e - 4];
        const float Pf = __uint_as_float(pq << 16);
        const float Qf = __uint_as_float(pq & 0xffff0000u);
        const int m0 = bitmask(wsh0, e);
        const int m1 = bitmask(wsh1, e);
        float w0 = fmaxf(A0 * Pf, B0 * Qf);
        w0 = __int_as_float(__float_as_int(w0) & m0);
        af0[e] = (short)__builtin_bit_cast(unsigned short, __float2bfloat16(w0));
        float w1 = fmaxf(A1 * Pf, B1 * Qf);
        w1 = __int_as_float(__float_as_int(w1) & m1);
        af1[e] = (short)__builtin_bit_cast(unsigned short, __float2bfloat16(w1));
      }
      __builtin_amdgcn_s_setprio(1);
      acc00 = __builtin_amdgcn_mfma_f32_16x16x32_bf16(af0, hv0, acc00, 0, 0, 0);
      acc01 = __builtin_amdgcn_mfma_f32_16x16x32_bf16(af0, hv1, acc01, 0, 0, 0);
      acc10 = __builtin_amdgcn_mfma_f32_16x16x32_bf16(af1, hv0, acc10, 0, 0, 0);
      acc11 = __builtin_amdgcn_mfma_f32_16x16x32_bf16(af1, hv1, acc11, 0, 0, 0);
      accS0 = __builtin_amdgcn_mfma_f32_16x16x32_bf16(af0, ones, accS0, 0, 0, 0);
      accS1 = __builtin_amdgcn_mfma_f32_16x16x32_bf16(af1, ones, accS1, 0, 0, 0);
      __builtin_amdgcn_s_setprio(0);
    }
    if (s < 7) {  // wave-private dbuf: no barrier needed
      *(int4*)(nxt + woff) = n0;
      *(int4*)(nxt + woff + 1 * 512) = n1;
      *(int4*)(nxt + woff + 2 * 512) = n2;
      *(int4*)(nxt + woff + 3 * 512) = n3;
      pqa0_c = pqa0_n; pqb0_c = pqb0_n;
      pqa1_c = pqa1_n; pqb1_c = pqb1_n;
    }
  }

  // epilogue combine: alias part/sp onto the (now dead) staging LDS
  __syncthreads();
  float (*part)[32][33] = (float (*)[32][33]) & smem[0][0][0];  // 16896 B
  float (*sp)[2][16] = (float (*)[2][16])((char*)&smem[0][0][0] + 16896);

#pragma unroll
  for (int r = 0; r < 4; ++r) {
    const int rl = lg * 4 + r;   // C row = (lane>>4)*4 + reg
    part[w][rl][lm] = acc00[r];
    part[w][rl][16 + lm] = acc01[r];
    part[w][16 + rl][lm] = acc10[r];
    part[w][16 + rl][16 + lm] = acc11[r];
  }
  if (lm == 0) {
#pragma unroll
    for (int r = 0; r < 4; ++r) {
      sp[w][0][lg * 4 + r] = accS0[r];  // every col holds the row-sum
      sp[w][1][lg * 4 + r] = accS1[r];
    }
  }
  __syncthreads();

  const int tid = threadIdx.x;
#pragma unroll
  for (int t = 0; t < 4; ++t) {
    const int idx = t * 256 + tid;
    const int row = idx >> 5, d = idx & 31;
    const float v = part[0][row][d] + part[1][row][d] +
                    part[2][row][d] + part[3][row][d];
    const float s = sp[0][row >> 4][row & 15] + sp[1][row >> 4][row & 15] +
                    sp[2][row >> 4][row & 15] + sp[3][row >> 4][row & 15];
    const float o = v / s;
    const int n = it * 32 + row;
    out[((size_t)b * NN + n) * 128 + head * 32 + d] =
        o > 0.f ? o : (__expf(o) - 1.f);
  }
}

extern "C" void kernel_launch(void* const* d_in, const int* in_sizes, int n_in,
                              void* d_out, int out_size, void* d_ws, size_t ws_size,
                              hipStream_t stream) {
  const float* x = (const float*)d_in[0];
  const int* adj = (const int*)d_in[1];
  const float* W = (const float*)d_in[2];
  const float* a = (const float*)d_in[3];
  float* out = (float*)d_out;
  float* ws = (float*)d_ws;

  float* e_src = ws + OFF_ES;
  float* e_dst = ws + OFF_ED;
  u32* PQv = (u32*)(ws + OFF_PQ);
  float* Mv = ws + OFF_M;
  u16* hT = (u16*)(ws + OFF_HT);
  u32* bits = (u32*)(ws + OFF_BITS);

  k_pp<<<2560, 256, 0, stream>>>(adj, bits, x, W, a, hT, e_src, e_dst);
  k_prep<<<BB * NH * 8, 64, 0, stream>>>(e_dst, PQv, Mv);
  k_attn<<<BB * NH * 64, 256, 0, stream>>>(hT, e_src, PQv, Mv, bits, out);
}

// Round 13
// 62.669 us; speedup vs baseline: 1.2496x; 1.2496x over previous
//
#include <hip/hip_runtime.h>
#include <hip/hip_bf16.h>

#define BB 4
#define NN 2048
#define FIN 128
#define NH 4
#define DH 32
#define NS 0.2f

typedef unsigned int u32;
typedef unsigned short u16;
typedef unsigned long long u64;
typedef __attribute__((ext_vector_type(8))) short short8;
typedef __attribute__((ext_vector_type(4))) float f32x4;
typedef __attribute__((ext_vector_type(4))) unsigned int u32x4;

// ws float offsets
#define OFF_ES 0          // [16][2048] f32
#define OFF_PQ 65536      // [16][2048] u32 (bf16 Q hi | bf16 P lo)
#define OFF_HT 131088     // u16 [16][32][2048] = 1048576 u16 = 524288 floats
#define OFF_BITS 655376   // u32 [4][2048][64] = 524288 u32

__device__ __forceinline__ u16 f2bf_rne(float f) {
  unsigned u = __float_as_uint(f);
  return (u16)((u + 0x7fffu + ((u >> 16) & 1u)) >> 16);
}

__device__ __forceinline__ int bitmask(u32 w, int e) {
#if __has_builtin(__builtin_amdgcn_sbfe)
  return __builtin_amdgcn_sbfe((int)w, e, 1);     // v_bfe_i32: 0 or -1
#else
  return ((int)(w << (31 - e))) >> 31;
#endif
}

// ---------------- K0: pack adj -> bitmask (0 LDS, full occupancy) -----------
__global__ __launch_bounds__(256) void k_pack(const int* __restrict__ adj,
                                              u32* __restrict__ bits) {
  const int row = (blockIdx.x << 2) | (threadIdx.x >> 6);  // b*2048+i
  const int lane = threadIdx.x & 63;
  const int* src = adj + (size_t)row * NN;
  u32* dst = bits + (size_t)row * 64;
#pragma unroll 8
  for (int it = 0; it < 32; ++it) {
    const int v = src[it * 64 + lane];
    const u64 m = __ballot(v != 0);
    if (lane == 0) *(u64*)(dst + it * 2) = m;
  }
}

// ---------------- K1: projection + e_src + P/Q tables + bf16 hT -------------
// No max-shift needed: softmax quotient is shift-invariant and unshifted
// exp args are bounded (~e^9) well inside fp32/bf16 range.
__global__ __launch_bounds__(256) void k_proj(
    const float* __restrict__ x, const float* __restrict__ W,
    const float* __restrict__ a, u16* __restrict__ hT,
    float* __restrict__ e_src, u32* __restrict__ PQ) {
  __shared__ float Ws[FIN * 128];
  const int tid = threadIdx.x;
  const int f = tid & 127, g = tid >> 7;
  const float4* Wg4 = (const float4*)W;
  float4* Ws4 = (float4*)Ws;
#pragma unroll
  for (int t = 0; t < 16; ++t) Ws4[t * 256 + tid] = Wg4[t * 256 + tid];
  __syncthreads();

  const int rb = blockIdx.x * 16 + g * 8;
  const int head = f >> 5, d = f & 31;
  const int b = rb >> 11, n0 = rb & (NN - 1);
  const int bh = b * NH + head;
  const float a_s = a[head * (2 * DH) + d];
  const float a_d = a[head * (2 * DH) + DH + d];

  float acc[8];
#pragma unroll
  for (int r = 0; r < 8; ++r) acc[r] = 0.f;

  const float* xb = x + (size_t)rb * FIN;  // wave-uniform -> s_loads
  for (int k = 0; k < FIN; ++k) {
    const float wv = Ws[k * 128 + f];
#pragma unroll
    for (int r = 0; r < 8; ++r) acc[r] = fmaf(wv, xb[r * FIN + k], acc[r]);
  }

  u16 hs[8];
#pragma unroll
  for (int r = 0; r < 8; ++r) hs[r] = f2bf_rne(acc[r]);
  u16* dst = hT + ((size_t)bh * DH + d) * NN + n0;
  *(int4*)dst = *(int4*)&hs[0];

#pragma unroll
  for (int r = 0; r < 8; ++r) {
    float s1 = acc[r] * a_s;
    float s2 = acc[r] * a_d;
#pragma unroll
    for (int off = 16; off >= 1; off >>= 1) {
      s1 += __shfl_xor(s1, off);
      s2 += __shfl_xor(s2, off);
    }
    if (d == 0) {
      e_src[(size_t)bh * NN + n0 + r] = s1;
      const u32 pb = f2bf_rne(__expf(s2));        // P = exp(e_dst)
      const u32 qb = f2bf_rne(__expf(NS * s2));   // Q = exp(0.2 e_dst)
      PQ[(size_t)bh * NN + n0 + r] = (qb << 16) | pb;
    }
  }
}

// ---------------- K2: LDS-staged weights->MFMA->direct output ---------------
// 32 rows/block, 4 waves = 4 j-quarters, grid 1024. hT via wave-private LDS
// (coalesced, swizzled, dbuf, T14 issue-early); bits hoisted to registers;
// PQ at point of use (L2-hot; prefetch proved neutral in r11 and costs VGPR);
// denominators on the matrix pipe. VGPR clamped for >=4 waves/SIMD.
__global__ __launch_bounds__(256, 4) void k_attn(
    const u16* __restrict__ hT, const float* __restrict__ e_src,
    const u32* __restrict__ PQv, const u32* __restrict__ bits,
    float* __restrict__ out) {
  // [wave][dbuf][32 d][64 j] u16 = 32 KB; epilogue part/sp aliased on top.
  __shared__ __align__(16) u16 smem[4][2][32 * 64];

  const int bid = blockIdx.x;          // 16 bh x 64 row-tiles
  const int bh = bid >> 6;
  const int it = bid & 63;
  const int b = bh >> 2, head = bh & 3;

  const int w = threadIdx.x >> 6;      // j-quarter
  const int lane = threadIdx.x & 63;
  const int lg = lane >> 4, lm = lane & 15;

  const int i0 = it * 32 + lm;
  const int i1 = i0 + 16;
  const float es0 = e_src[(size_t)bh * NN + i0];
  const float es1 = e_src[(size_t)bh * NN + i1];
  const float A0 = __expf(es0), B0 = __expf(NS * es0);
  const float A1 = __expf(es1), B1 = __expf(NS * es1);
  // w = exp(lrelu(es+ed)) = max(A*P_j, B*Q_j)   (exp monotone, exact)

  const u32* PQb = PQv + (size_t)bh * NN + w * 512;
  const u16* hb = hT + (size_t)bh * DH * NN + w * 512;   // [d][j-quarter]
  const u32* br0 = bits + ((size_t)b * NN + i0) * 64 + w * 16;
  const u32* br1 = bits + ((size_t)b * NN + i1) * 64 + w * 16;
  const int shamt = lg * 8;
  const int jb = lg * 8;

  // hoist ALL bits for this wave's j-quarter into registers (8 x int4 loads)
  u32 wd0[16], wd1[16];
#pragma unroll
  for (int q = 0; q < 4; ++q) {
    const u32x4 v0 = *(const u32x4*)(br0 + q * 4);
    const u32x4 v1 = *(const u32x4*)(br1 + q * 4);
#pragma unroll
    for (int k2 = 0; k2 < 4; ++k2) { wd0[q * 4 + k2] = v0[k2]; wd1[q * 4 + k2] = v1[k2]; }
  }

  // staging lane roles: instr t loads data rows d = t*8+sd, 16B at j-offset sj.
  const int sd = lane >> 3;
  const int sj = (lane & 7) * 8;
  u16* stg0 = &smem[w][0][0];
  u16* stg1 = &smem[w][1][0];
  const int woff = (sd * 64 + sj) ^ (sd << 3);   // row sd, swizzle (d&7)<<3

  short8 ones;
#pragma unroll
  for (int e = 0; e < 8; ++e) ones[e] = (short)0x3F80;  // bf16 1.0

  f32x4 acc00 = {0,0,0,0}, acc01 = {0,0,0,0};
  f32x4 acc10 = {0,0,0,0}, acc11 = {0,0,0,0};
  f32x4 accS0 = {0,0,0,0}, accS1 = {0,0,0,0};

  // prologue: stage superchunk 0
  {
    int4 r0 = *(const int4*)(hb + (size_t)(0 * 8 + sd) * NN + sj);
    int4 r1 = *(const int4*)(hb + (size_t)(1 * 8 + sd) * NN + sj);
    int4 r2 = *(const int4*)(hb + (size_t)(2 * 8 + sd) * NN + sj);
    int4 r3 = *(const int4*)(hb + (size_t)(3 * 8 + sd) * NN + sj);
    *(int4*)(stg0 + woff) = r0;
    *(int4*)(stg0 + woff + 1 * 512) = r1;
    *(int4*)(stg0 + woff + 2 * 512) = r2;
    *(int4*)(stg0 + woff + 3 * 512) = r3;
  }

  const int ra0 = (lm * 64) ^ ((lm & 7) << 3);  // swizzled base for d=lm row

#pragma unroll
  for (int s = 0; s < 8; ++s) {
    u16* cur = (s & 1) ? stg1 : stg0;
    u16* nxt = (s & 1) ? stg0 : stg1;
    int4 n0, n1, n2, n3;
    if (s < 7) {  // issue next-s hT loads before this s's compute (T14)
      const u16* g = hb + (s + 1) * 64;
      n0 = *(const int4*)(g + (size_t)(0 * 8 + sd) * NN + sj);
      n1 = *(const int4*)(g + (size_t)(1 * 8 + sd) * NN + sj);
      n2 = *(const int4*)(g + (size_t)(2 * 8 + sd) * NN + sj);
      n3 = *(const int4*)(g + (size_t)(3 * 8 + sd) * NN + sj);
    }
#pragma unroll
    for (int c = 0; c < 2; ++c) {
      const int jl = c * 32 + jb;
      const u32x4 pqa = *(const u32x4*)(PQb + s * 64 + jl);       // L2-hot
      const u32x4 pqb = *(const u32x4*)(PQb + s * 64 + jl + 4);
      const short8 hv0 = *(const short8*)(cur + (ra0 ^ jl));
      const short8 hv1 = *(const short8*)(cur + ((ra0 ^ jl) + 16 * 64));
      const u32 wsh0 = wd0[s * 2 + c] >> shamt;   // static index (unrolled)
      const u32 wsh1 = wd1[s * 2 + c] >> shamt;
      short8 af0, af1;
#pragma unroll
      for (int e = 0; e < 8; ++e) {
        const u32 pq = (e < 4) ? pqa[e] : pqb[e - 4];
        const float Pf = __uint_as_float(pq << 16);
        const float Qf = __uint_as_float(pq & 0xffff0000u);
        const int m0 = bitmask(wsh0, e);
        const int m1 = bitmask(wsh1, e);
        float w0 = fmaxf(A0 * Pf, B0 * Qf);
        w0 = __int_as_float(__float_as_int(w0) & m0);
        af0[e] = (short)__builtin_bit_cast(unsigned short, __float2bfloat16(w0));
        float w1 = fmaxf(A1 * Pf, B1 * Qf);
        w1 = __int_as_float(__float_as_int(w1) & m1);
        af1[e] = (short)__builtin_bit_cast(unsigned short, __float2bfloat16(w1));
      }
      __builtin_amdgcn_s_setprio(1);
      acc00 = __builtin_amdgcn_mfma_f32_16x16x32_bf16(af0, hv0, acc00, 0, 0, 0);
      acc01 = __builtin_amdgcn_mfma_f32_16x16x32_bf16(af0, hv1, acc01, 0, 0, 0);
      acc10 = __builtin_amdgcn_mfma_f32_16x16x32_bf16(af1, hv0, acc10, 0, 0, 0);
      acc11 = __builtin_amdgcn_mfma_f32_16x16x32_bf16(af1, hv1, acc11, 0, 0, 0);
      accS0 = __builtin_amdgcn_mfma_f32_16x16x32_bf16(af0, ones, accS0, 0, 0, 0);
      accS1 = __builtin_amdgcn_mfma_f32_16x16x32_bf16(af1, ones, accS1, 0, 0, 0);
      __builtin_amdgcn_s_setprio(0);
    }
    if (s < 7) {  // wave-private dbuf: no barrier needed
      *(int4*)(nxt + woff) = n0;
      *(int4*)(nxt + woff + 1 * 512) = n1;
      *(int4*)(nxt + woff + 2 * 512) = n2;
      *(int4*)(nxt + woff + 3 * 512) = n3;
    }
  }

  // epilogue combine: alias part/sp onto the (now dead) staging LDS
  __syncthreads();
  float (*part)[32][33] = (float (*)[32][33]) & smem[0][0][0];  // 16896 B
  float (*sp)[2][16] = (float (*)[2][16])((char*)&smem[0][0][0] + 16896);

#pragma unroll
  for (int r = 0; r < 4; ++r) {
    const int rl = lg * 4 + r;   // C row = (lane>>4)*4 + reg
    part[w][rl][lm] = acc00[r];
    part[w][rl][16 + lm] = acc01[r];
    part[w][16 + rl][lm] = acc10[r];
    part[w][16 + rl][16 + lm] = acc11[r];
  }
  if (lm == 0) {
#pragma unroll
    for (int r = 0; r < 4; ++r) {
      sp[w][0][lg * 4 + r] = accS0[r];  // every col holds the row-sum
      sp[w][1][lg * 4 + r] = accS1[r];
    }
  }
  __syncthreads();

  const int tid = threadIdx.x;
#pragma unroll
  for (int t = 0; t < 4; ++t) {
    const int idx = t * 256 + tid;
    const int row = idx >> 5, d = idx & 31;
    const float v = part[0][row][d] + part[1][row][d] +
                    part[2][row][d] + part[3][row][d];
    const float s = sp[0][row >> 4][row & 15] + sp[1][row >> 4][row & 15] +
                    sp[2][row >> 4][row & 15] + sp[3][row >> 4][row & 15];
    const float o = v / s;
    const int n = it * 32 + row;
    out[((size_t)b * NN + n) * 128 + head * 32 + d] =
        o > 0.f ? o : (__expf(o) - 1.f);
  }
}

extern "C" void kernel_launch(void* const* d_in, const int* in_sizes, int n_in,
                              void* d_out, int out_size, void* d_ws, size_t ws_size,
                              hipStream_t stream) {
  const float* x = (const float*)d_in[0];
  const int* adj = (const int*)d_in[1];
  const float* W = (const float*)d_in[2];
  const float* a = (const float*)d_in[3];
  float* out = (float*)d_out;
  float* ws = (float*)d_ws;

  float* e_src = ws + OFF_ES;
  u32* PQv = (u32*)(ws + OFF_PQ);
  u16* hT = (u16*)(ws + OFF_HT);
  u32* bits = (u32*)(ws + OFF_BITS);

  k_pack<<<(BB * NN) / 4, 256, 0, stream>>>(adj, bits);
  k_proj<<<(BB * NN) / 16, 256, 0, stream>>>(x, W, a, hT, e_src, PQv);
  k_attn<<<BB * NH * 64, 256, 0, stream>>>(hT, e_src, PQv, bits, out);
}